// Round 17
// baseline (188.158 us; speedup 1.0000x reference)
//
#include <hip/hip_runtime.h>
#include <math.h>

#define NN 50000
#define NE 800000
#define NEP 850000          // NE + NN self loops
#define FI 1284
#define HD 128
#define KP 1312             // FI padded to 41*32 for MFMA K-loop
#define NSTEP 41            // KP/32
#define NH (NN * HD)        // 6,400,000
#define PAD 64              // per-dst CSR bucket (Poisson(17): P(deg>64) ~ 1e-20)
#define NBLK ((NN + 255) / 256)             // 196
#define BM 208                               // rows/block (13 waves x 16)
#define NROWB ((NN + BM - 1) / BM)          // 241 blocks -> ~1/CU, balanced
#define WP_ELEMS (NSTEP * 4096)             // packed B: 41 steps * 8cg * 64lane * 8
#define WT_BLKS ((WP_ELEMS + 255) / 256)    // 657

typedef float f32x4 __attribute__((ext_vector_type(4)));
typedef short bfrag __attribute__((ext_vector_type(8)));   // 8 bf16 in 4 VGPRs

// ---------------- helpers ----------------

__device__ __forceinline__ float wave_reduce_sum(float v) {
    #pragma unroll
    for (int off = 32; off; off >>= 1) v += __shfl_down(v, off);
    return v;
}

__device__ __forceinline__ ushort f2bf(float f) {   // RNE fp32->bf16 bits
    unsigned u = __float_as_uint(f);
    u += 0x7FFFu + ((u >> 16) & 1u);
    return (ushort)(u >> 16);
}

__device__ __forceinline__ float bf2f(ushort u) {
    return __uint_as_float(((unsigned)u) << 16);
}

__device__ __forceinline__ ushort f2h(float f) {    // fp32 -> fp16 bits (RNE)
    _Float16 h = (_Float16)f;
    return *(ushort*)&h;
}

__device__ __forceinline__ float h2f(ushort u) {
    _Float16 h = *(_Float16*)&u;
    return (float)h;
}

// packed RNE convert: 4x v_cvt_pk_bf16_f32 (dst.lo=src0, dst.hi=src1)
__device__ __forceinline__ bfrag cvt_frag(float4 a0, float4 a1) {
    union { int i[4]; bfrag f; } u;
    asm("v_cvt_pk_bf16_f32 %0, %1, %2" : "=v"(u.i[0]) : "v"(a0.x), "v"(a0.y));
    asm("v_cvt_pk_bf16_f32 %0, %1, %2" : "=v"(u.i[1]) : "v"(a0.z), "v"(a0.w));
    asm("v_cvt_pk_bf16_f32 %0, %1, %2" : "=v"(u.i[2]) : "v"(a1.x), "v"(a1.y));
    asm("v_cvt_pk_bf16_f32 %0, %1, %2" : "=v"(u.i[3]) : "v"(a1.z), "v"(a1.w));
    return u.f;
}

// ---------------- fused preamble: cursor init | consts | Wp pack | sum_attr partials ----------------

__global__ __launch_bounds__(256) void k_pre(int* cursor, float* sc,
                                             const float* We1, const float* ae1,
                                             const float* We2, const float* ae2,
                                             const float* __restrict__ W, ushort* __restrict__ Wp,
                                             const float* __restrict__ eattr, float* bsum) {
    int b = blockIdx.x;
    if (b < NBLK) {
        int i = b * 256 + threadIdx.x;
        if (i < NN) cursor[i] = i * PAD;
    } else if (b == NBLK) {
        if (threadIdx.x < 64) {
            int l = threadIdx.x;
            float v = We1[l] * ae1[l] + We1[l + 64] * ae1[l + 64];
            v = wave_reduce_sum(v);
            if (l == 0) { sc[1] = v; sc[2] = We2[0] * ae2[0]; }
        }
    } else if (b < NBLK + 1 + WT_BLKS) {
        int i = (b - NBLK - 1) * 256 + threadIdx.x;
        if (i >= WP_ELEMS) return;
        int s = i >> 12;
        int r = i & 4095;
        int cg = r >> 9;
        int q = r & 511;
        int lane = q >> 3, j = q & 7;
        int k = s * 32 + (lane >> 4) * 8 + j;
        int c = cg * 16 + (lane & 15);
        float v = (k < FI) ? W[(size_t)k * HD + c] : 0.f;
        Wp[i] = f2bf(v);
    } else {
        __shared__ float wsum[4];
        int b2 = b - NBLK - 1 - WT_BLKS;   // 0..255
        float v = 0.f;
        for (int i = b2 * 256 + threadIdx.x; i < NE; i += 256 * 256)
            v += eattr[i];
        v = wave_reduce_sum(v);
        int wid = threadIdx.x >> 6, l = threadIdx.x & 63;
        if (l == 0) wsum[wid] = v;
        __syncthreads();
        if (threadIdx.x == 0)
            bsum[b2] = wsum[0] + wsum[1] + wsum[2] + wsum[3];
    }
}

// ---------------- GEMM1: h1 = x @ W1 (bf16 MFMA, BM=208, 13 waves, 3-buffer depth-2) ----------------
// 241 blocks ~ 1/CU (balanced). All waves stage their own A (2 insts); waves 0-7 also
// stage one 1KB B chunk (1 inst). Asymmetric counted vmcnt: waves<8 steady 6, waves>=8
// steady 4 (= 2 stages in flight each). Fused rowdot epilogue.

__global__ __launch_bounds__(832) void k_gemm1_mfma(const float* __restrict__ x,
                                                    const ushort* __restrict__ Wp,
                                                    ushort* __restrict__ h1,
                                                    const float* __restrict__ asrc,
                                                    const float* __restrict__ adst,
                                                    float* __restrict__ as1,
                                                    float* __restrict__ ad1,
                                                    const float* __restrict__ bsum,
                                                    float* sc) {
    __shared__ float  As[3][BM][32];    // 78 KB
    __shared__ ushort Bs[3][4096];      // 24 KB
    const int t = threadIdx.x;
    const int wid = t >> 6, l = t & 63;
    const int lr = l & 15, lg = l >> 4;
    const int wrow0 = blockIdx.x * BM + wid * 16;

    if (blockIdx.x == 0 && wid == 0) {   // finalize sum_attr (fixed order, deterministic)
        float v = bsum[l] + bsum[l + 64] + bsum[l + 128] + bsum[l + 192];
        v = wave_reduce_sum(v);
        if (l == 0) sc[0] = v;
    }

    const int srow = l >> 3;
    const int schunk = (l & 7) ^ srow;
    int g0 = wrow0 + srow;      if (g0 > NN - 1) g0 = NN - 1;
    int g1 = wrow0 + 8 + srow;  if (g1 > NN - 1) g1 = NN - 1;
    const float* sp0 = x + (size_t)g0 * FI + schunk * 4;
    const float* sp1 = x + (size_t)g1 * FI + schunk * 4;

    const ushort* bq0 = Wp + wid * 512 + l * 8;   // valid only for wid < 8

    const int rs0 = (lg * 2)     ^ (lr & 7);
    const int rs1 = (lg * 2 + 1) ^ (lr & 7);

    f32x4 acc[8];
    #pragma unroll
    for (int c = 0; c < 8; ++c) acc[c] = (f32x4){0.f, 0.f, 0.f, 0.f};

#define STAGE(B, IT) do { \
    __builtin_amdgcn_global_load_lds( \
        (const __attribute__((address_space(1))) unsigned int*)(sp0 + (size_t)(IT) * 32), \
        (__attribute__((address_space(3))) unsigned int*)&As[B][wid * 16][0], 16, 0, 0); \
    __builtin_amdgcn_global_load_lds( \
        (const __attribute__((address_space(1))) unsigned int*)(sp1 + (size_t)(IT) * 32), \
        (__attribute__((address_space(3))) unsigned int*)&As[B][wid * 16 + 8][0], 16, 0, 0); \
    if (wid < 8) \
        __builtin_amdgcn_global_load_lds( \
            (const __attribute__((address_space(1))) unsigned int*)(bq0 + (size_t)(IT) * 4096), \
            (__attribute__((address_space(3))) unsigned int*)&Bs[B][wid * 512], 16, 0, 0); \
} while (0)

// steady-state: 3 stages issued, wait until oldest landed (2 stages stay in flight)
#define WAIT_STEADY() do { \
    if (wid < 8) asm volatile("s_waitcnt vmcnt(6)" ::: "memory"); \
    else         asm volatile("s_waitcnt vmcnt(4)" ::: "memory"); \
} while (0)
#define WAIT_1LEFT() do { \
    if (wid < 8) asm volatile("s_waitcnt vmcnt(3)" ::: "memory"); \
    else         asm volatile("s_waitcnt vmcnt(2)" ::: "memory"); \
} while (0)

    STAGE(0, 0);
    STAGE(1, 1);
    STAGE(2, 2);
    WAIT_STEADY();                                      // stage 0 landed
    __builtin_amdgcn_s_barrier();

    int bsel = 0;
    for (int it = 0; it < 40; ++it) {
        bfrag bfr[8];
        #pragma unroll
        for (int cg = 0; cg < 8; ++cg)
            bfr[cg] = *(const bfrag*)&Bs[bsel][cg * 512 + l * 8];

        float4 a0 = *(const float4*)&As[bsel][wid * 16 + lr][rs0 * 4];
        float4 a1 = *(const float4*)&As[bsel][wid * 16 + lr][rs1 * 4];
        bfrag af = cvt_frag(a0, a1);
        #pragma unroll
        for (int cg = 0; cg < 8; ++cg)
            acc[cg] = __builtin_amdgcn_mfma_f32_16x16x32_bf16(af, bfr[cg], acc[cg], 0, 0, 0);

        __builtin_amdgcn_s_barrier();                   // all waves done READING buf[bsel]
        if (it + 3 < 40) {
            STAGE(bsel, it + 3);
            WAIT_STEADY();                              // stage(it+1) landed
        } else if (it == 37) {
            WAIT_1LEFT();                               // stage(38) landed
        } else if (it == 38) {
            asm volatile("s_waitcnt vmcnt(0)" ::: "memory");  // stage(39) landed
        }
        __builtin_amdgcn_s_barrier();                   // staged writes visible to all waves
        bsel = (bsel == 2) ? 0 : bsel + 1;
    }
#undef STAGE
#undef WAIT_STEADY
#undef WAIT_1LEFT

    {   // K tail: step 40 (k0=1280, valid k<1284 in lg==0 low half); Wp zero-padded
        int rowc = wrow0 + lr; if (rowc > NN - 1) rowc = NN - 1;
        float4 a0t = make_float4(0.f, 0.f, 0.f, 0.f);
        if (lg == 0) a0t = *(const float4*)(x + (size_t)rowc * FI + 1280);
        bfrag af;
        af[0] = (short)f2bf(a0t.x); af[1] = (short)f2bf(a0t.y);
        af[2] = (short)f2bf(a0t.z); af[3] = (short)f2bf(a0t.w);
        af[4] = 0; af[5] = 0; af[6] = 0; af[7] = 0;
        const ushort* wqs = Wp + (size_t)40 * 4096 + l * 8;
        #pragma unroll
        for (int cg = 0; cg < 8; ++cg) {
            bfrag bf = *(const bfrag*)(wqs + cg * 512);
            acc[cg] = __builtin_amdgcn_mfma_f32_16x16x32_bf16(af, bf, acc[cg], 0, 0, 0);
        }
    }

    // h1 store (bf16)
    #pragma unroll
    for (int cg = 0; cg < 8; ++cg) {
        #pragma unroll
        for (int r = 0; r < 4; ++r) {
            int gr = wrow0 + lg * 4 + r;
            if (gr < NN) h1[(size_t)gr * HD + cg * 16 + lr] = f2bf(acc[cg][r]);
        }
    }

    // fused rowdot epilogue: as1/ad1[row] from fp32 acc (shfl_xor over 16-lane lr group)
    float av[8], dv[8];
    #pragma unroll
    for (int cg = 0; cg < 8; ++cg) {
        av[cg] = asrc[cg * 16 + lr];
        dv[cg] = adst[cg * 16 + lr];
    }
    #pragma unroll
    for (int r = 0; r < 4; ++r) {
        float s = 0.f, d = 0.f;
        #pragma unroll
        for (int cg = 0; cg < 8; ++cg) {
            s += acc[cg][r] * av[cg];
            d += acc[cg][r] * dv[cg];
        }
        #pragma unroll
        for (int off = 1; off < 16; off <<= 1) {
            s += __shfl_xor(s, off);
            d += __shfl_xor(d, off);
        }
        int gr = wrow0 + lg * 4 + r;
        if (lr == 0 && gr < NN) { as1[gr] = s; ad1[gr] = d; }
    }
}

// ---------------- place: fixed-bucket CSR (d*PAD), packed 8B record {src, al_h<<16 | attr_h} ----------------

__global__ void k_place(const int* __restrict__ ei, const float* __restrict__ eattr,
                        const float* __restrict__ sc,
                        const float* __restrict__ as1, const float* __restrict__ ad1,
                        int* cursor, int2* __restrict__ csr) {
    int e = blockIdx.x * blockDim.x + threadIdx.x;
    if (e >= NEP) return;
    int s, d; float av;
    if (e < NE) { s = ei[e]; d = ei[NE + e]; av = eattr[e]; }
    else        { s = d = e - NE; av = sc[0] * (1.0f / NE); }
    float a = as1[s] + ad1[d] + sc[1] * av;
    a = (a > 0.f) ? a : 0.2f * a;
    int pos = atomicAdd(&cursor[d], 1);
    if (pos - d * PAD < PAD)   // never taken for this input; memory-safety guard
        csr[pos] = make_int2(s, ((int)f2h(a) << 16) | (int)f2h(av));
}

// ---------------- layer 1 (fused): single-pass ONLINE softmax + PV + ELU + W2-dot ----------------

__global__ __launch_bounds__(256) void k_layer1(const int2* __restrict__ csr,
                                                const int* __restrict__ cursor,
                                                const ushort* __restrict__ h1,
                                                const float* __restrict__ b1,
                                                const float* __restrict__ W2,
                                                float* __restrict__ h2) {
    int wid = threadIdx.x >> 6, l = threadIdx.x & 63;
    int d = blockIdx.x * 4 + wid;
    if (d >= NN) return;
    int s0 = d * PAD;
    int n = cursor[d] - s0; if (n > PAD) n = PAD;

    float m = -INFINITY, den = 0.f, ax = 0.f, ay = 0.f;
    int i = 0;
    for (; i + 4 <= n; i += 4) {
        int2 e0 = csr[s0 + i],     e1 = csr[s0 + i + 1];
        int2 e2 = csr[s0 + i + 2], e3 = csr[s0 + i + 3];
        float a0 = h2f((ushort)(e0.y >> 16));
        float a1 = h2f((ushort)(e1.y >> 16));
        float a2 = h2f((ushort)(e2.y >> 16));
        float a3 = h2f((ushort)(e3.y >> 16));
        ushort2 hv0 = *(const ushort2*)&h1[(size_t)e0.x * HD + 2 * l];
        ushort2 hv1 = *(const ushort2*)&h1[(size_t)e1.x * HD + 2 * l];
        ushort2 hv2 = *(const ushort2*)&h1[(size_t)e2.x * HD + 2 * l];
        ushort2 hv3 = *(const ushort2*)&h1[(size_t)e3.x * HD + 2 * l];
        float mt = fmaxf(fmaxf(a0, a1), fmaxf(a2, a3));
        if (mt > m) {                      // wave-uniform branch
            float r = expf(m - mt);        // first tile: exp(-inf) = 0
            den *= r; ax *= r; ay *= r; m = mt;
        }
        float w0 = expf(a0 - m), w1 = expf(a1 - m);
        float w2 = expf(a2 - m), w3 = expf(a3 - m);
        den += w0 + w1 + w2 + w3;
        ax += w0 * bf2f(hv0.x) + w1 * bf2f(hv1.x) + w2 * bf2f(hv2.x) + w3 * bf2f(hv3.x);
        ay += w0 * bf2f(hv0.y) + w1 * bf2f(hv1.y) + w2 * bf2f(hv2.y) + w3 * bf2f(hv3.y);
    }
    for (; i < n; ++i) {
        int2 e0 = csr[s0 + i];
        float a0 = h2f((ushort)(e0.y >> 16));
        ushort2 hv0 = *(const ushort2*)&h1[(size_t)e0.x * HD + 2 * l];
        if (a0 > m) {
            float r = expf(m - a0);
            den *= r; ax *= r; ay *= r; m = a0;
        }
        float w0 = expf(a0 - m);
        den += w0;
        ax += w0 * bf2f(hv0.x);
        ay += w0 * bf2f(hv0.y);
    }
    float inv = 1.f / (den + 1e-16f);
    ax *= inv; ay *= inv;
    float2 bb = *(const float2*)&b1[2 * l];
    float2 w  = *(const float2*)&W2[2 * l];
    float a = ax + bb.x; a = (a > 0.f) ? a : (expf(a) - 1.f);
    float b = ay + bb.y; b = (b > 0.f) ? b : (expf(b) - 1.f);
    float p = a * w.x + b * w.y;
    p = wave_reduce_sum(p);
    if (l == 0) h2[d] = p;
}

// ---------------- layer 2 (fused, scalar): single-pass online softmax ----------------

__global__ __launch_bounds__(256) void k_layer2(const int2* __restrict__ csr,
                                                const int* __restrict__ cursor,
                                                const float* __restrict__ h2,
                                                const float* __restrict__ as2,
                                                const float* __restrict__ ad2,
                                                const float* __restrict__ sc,
                                                const float* __restrict__ b2,
                                                float* __restrict__ out) {
    int d = blockIdx.x * blockDim.x + threadIdx.x;
    if (d >= NN) return;
    int s0 = d * PAD;
    int n = cursor[d] - s0; if (n > PAD) n = PAD;
    float A = as2[0], D = ad2[0], c2 = sc[2];
    float hd = D * h2[d];

    float m = -INFINITY, den = 0.f, num = 0.f;
    int i = 0;
    for (; i + 4 <= n; i += 4) {
        int2 s_0 = csr[s0 + i],     s_1 = csr[s0 + i + 1];
        int2 s_2 = csr[s0 + i + 2], s_3 = csr[s0 + i + 3];
        float h0 = h2[s_0.x], h1v = h2[s_1.x], h2v = h2[s_2.x], h3 = h2[s_3.x];
        float a0 = A * h0 + hd + c2 * h2f((ushort)(s_0.y & 0xFFFF));
        float a1 = A * h1v + hd + c2 * h2f((ushort)(s_1.y & 0xFFFF));
        float a2 = A * h2v + hd + c2 * h2f((ushort)(s_2.y & 0xFFFF));
        float a3 = A * h3 + hd + c2 * h2f((ushort)(s_3.y & 0xFFFF));
        a0 = (a0 > 0.f) ? a0 : 0.2f * a0;
        a1 = (a1 > 0.f) ? a1 : 0.2f * a1;
        a2 = (a2 > 0.f) ? a2 : 0.2f * a2;
        a3 = (a3 > 0.f) ? a3 : 0.2f * a3;
        float mt = fmaxf(fmaxf(a0, a1), fmaxf(a2, a3));
        if (mt > m) {
            float r = expf(m - mt);
            den *= r; num *= r; m = mt;
        }
        float w0 = expf(a0 - m), w1 = expf(a1 - m);
        float w2 = expf(a2 - m), w3 = expf(a3 - m);
        den += w0 + w1 + w2 + w3;
        num += w0 * h0 + w1 * h1v + w2 * h2v + w3 * h3;
    }
    for (; i < n; ++i) {
        int2 sa = csr[s0 + i];
        float hs = h2[sa.x];
        float a = A * hs + hd + c2 * h2f((ushort)(sa.y & 0xFFFF));
        a = (a > 0.f) ? a : 0.2f * a;
        if (a > m) {
            float r = expf(m - a);
            den *= r; num *= r; m = a;
        }
        float wgt = expf(a - m);
        den += wgt;
        num += wgt * hs;
    }
    float v = num / (den + 1e-16f) + b2[0];
    out[d] = (v >= 0.f) ? v : 0.01f * v;
}

// ---------------- launch ----------------

extern "C" void kernel_launch(void* const* d_in, const int* in_sizes, int n_in,
                              void* d_out, int out_size, void* d_ws, size_t ws_size,
                              hipStream_t stream) {
    const float* x     = (const float*)d_in[0];
    const int*   ei    = (const int*)d_in[1];
    const float* eattr = (const float*)d_in[2];
    const float* W1    = (const float*)d_in[3];
    const float* asrc1 = (const float*)d_in[4];
    const float* adst1 = (const float*)d_in[5];
    const float* We1   = (const float*)d_in[6];
    const float* ae1   = (const float*)d_in[7];
    const float* b1    = (const float*)d_in[8];
    const float* W2    = (const float*)d_in[9];
    const float* as2   = (const float*)d_in[10];
    const float* ad2   = (const float*)d_in[11];
    const float* We2   = (const float*)d_in[12];
    const float* ae2   = (const float*)d_in[13];
    const float* b2    = (const float*)d_in[14];
    float* out = (float*)d_out;

    // workspace layout (~40 MB)
    ushort* h1  = (ushort*)d_ws;              // NH ushorts (12.8 MB)
    float* as1  = (float*)(h1 + (size_t)NH);  // NN
    float* ad1  = as1 + NN;
    float* h2   = ad1 + NN;
    float* sc   = h2 + NN;                    // 8 scalars
    float* bsum = sc + 8;                     // 256 partials
    int*   cursor = (int*)(bsum + 256);       // NN
    int2*  csr    = (int2*)(cursor + NN);     // NN*PAD int2 (25.6 MB)
    ushort* Wp  = (ushort*)(csr + (size_t)NN * PAD);  // WP_ELEMS bf16 (packed)

    k_pre<<<NBLK + 1 + WT_BLKS + 256, 256, 0, stream>>>(cursor, sc, We1, ae1, We2, ae2,
                                                        W1, Wp, eattr, bsum);

    k_gemm1_mfma<<<NROWB, 832, 0, stream>>>(x, Wp, h1, asrc1, adst1, as1, ad1, bsum, sc);

    k_place<<<(NEP + 255) / 256, 256, 0, stream>>>(ei, eattr, sc, as1, ad1, cursor, csr);

    k_layer1<<<(NN + 3) / 4, 256, 0, stream>>>(csr, cursor, h1, b1, W2, h2);
    k_layer2<<<(NN + 255) / 256, 256, 0, stream>>>(csr, cursor, h2, as2, ad2, sc, b2, out);
}

// Round 18
// 183.002 us; speedup vs baseline: 1.0282x; 1.0282x over previous
//
#include <hip/hip_runtime.h>
#include <math.h>

#define NN 50000
#define NE 800000
#define NEP 850000          // NE + NN self loops
#define FI 1284
#define HD 128
#define KP 1312             // FI padded to 41*32 for MFMA K-loop
#define NSTEP 41            // KP/32
#define NH (NN * HD)        // 6,400,000
#define PAD 64              // per-dst CSR bucket (Poisson(17): P(deg>64) ~ 1e-20)
#define NBLK ((NN + 255) / 256)             // 196
#define NROWB ((NN + 127) / 128)            // 391 row-blocks of 128
#define WP_ELEMS (NSTEP * 4096)             // packed B: 41 steps * 8cg * 64lane * 8
#define WT_BLKS ((WP_ELEMS + 255) / 256)    // 657

typedef float f32x4 __attribute__((ext_vector_type(4)));
typedef short bfrag __attribute__((ext_vector_type(8)));   // 8 bf16 in 4 VGPRs

// ---------------- helpers ----------------

__device__ __forceinline__ float wave_reduce_sum(float v) {
    #pragma unroll
    for (int off = 32; off; off >>= 1) v += __shfl_down(v, off);
    return v;
}

__device__ __forceinline__ ushort f2bf(float f) {   // RNE fp32->bf16 bits
    unsigned u = __float_as_uint(f);
    u += 0x7FFFu + ((u >> 16) & 1u);
    return (ushort)(u >> 16);
}

__device__ __forceinline__ float bf2f(ushort u) {
    return __uint_as_float(((unsigned)u) << 16);
}

__device__ __forceinline__ ushort f2h(float f) {    // fp32 -> fp16 bits (RNE)
    _Float16 h = (_Float16)f;
    return *(ushort*)&h;
}

__device__ __forceinline__ float h2f(ushort u) {
    _Float16 h = *(_Float16*)&u;
    return (float)h;
}

// packed RNE convert: 4x v_cvt_pk_bf16_f32 (dst.lo=src0, dst.hi=src1)
__device__ __forceinline__ bfrag cvt_frag(float4 a0, float4 a1) {
    union { int i[4]; bfrag f; } u;
    asm("v_cvt_pk_bf16_f32 %0, %1, %2" : "=v"(u.i[0]) : "v"(a0.x), "v"(a0.y));
    asm("v_cvt_pk_bf16_f32 %0, %1, %2" : "=v"(u.i[1]) : "v"(a0.z), "v"(a0.w));
    asm("v_cvt_pk_bf16_f32 %0, %1, %2" : "=v"(u.i[2]) : "v"(a1.x), "v"(a1.y));
    asm("v_cvt_pk_bf16_f32 %0, %1, %2" : "=v"(u.i[3]) : "v"(a1.z), "v"(a1.w));
    return u.f;
}

// ---------------- fused preamble: cursor init | consts | Wp pack | sum_attr partials ----------------

__global__ __launch_bounds__(256) void k_pre(int* cursor, float* sc,
                                             const float* We1, const float* ae1,
                                             const float* We2, const float* ae2,
                                             const float* __restrict__ W, ushort* __restrict__ Wp,
                                             const float* __restrict__ eattr, float* bsum) {
    int b = blockIdx.x;
    if (b < NBLK) {
        int i = b * 256 + threadIdx.x;
        if (i < NN) cursor[i] = i * PAD;
    } else if (b == NBLK) {
        if (threadIdx.x < 64) {
            int l = threadIdx.x;
            float v = We1[l] * ae1[l] + We1[l + 64] * ae1[l + 64];
            v = wave_reduce_sum(v);
            if (l == 0) { sc[1] = v; sc[2] = We2[0] * ae2[0]; }
        }
    } else if (b < NBLK + 1 + WT_BLKS) {
        int i = (b - NBLK - 1) * 256 + threadIdx.x;
        if (i >= WP_ELEMS) return;
        int s = i >> 12;
        int r = i & 4095;
        int cg = r >> 9;
        int q = r & 511;
        int lane = q >> 3, j = q & 7;
        int k = s * 32 + (lane >> 4) * 8 + j;
        int c = cg * 16 + (lane & 15);
        float v = (k < FI) ? W[(size_t)k * HD + c] : 0.f;
        Wp[i] = f2bf(v);
    } else {
        __shared__ float wsum[4];
        int b2 = b - NBLK - 1 - WT_BLKS;   // 0..255
        float v = 0.f;
        for (int i = b2 * 256 + threadIdx.x; i < NE; i += 256 * 256)
            v += eattr[i];
        v = wave_reduce_sum(v);
        int wid = threadIdx.x >> 6, l = threadIdx.x & 63;
        if (l == 0) wsum[wid] = v;
        __syncthreads();
        if (threadIdx.x == 0)
            bsum[b2] = wsum[0] + wsum[1] + wsum[2] + wsum[3];
    }
}

// ---------------- GEMM1: h1 = x @ W1 (bf16 MFMA, BM=128, 8 waves, 3-buffer depth-2) ----------------
// R16-proven geometry. block 0 wave 0 also finalizes sc[0] = sum(bsum).

__global__ __launch_bounds__(512) void k_gemm1_mfma(const float* __restrict__ x,
                                                    const ushort* __restrict__ Wp,
                                                    ushort* __restrict__ h1,
                                                    const float* __restrict__ asrc,
                                                    const float* __restrict__ adst,
                                                    float* __restrict__ as1,
                                                    float* __restrict__ ad1,
                                                    const float* __restrict__ bsum,
                                                    float* sc) {
    __shared__ float  As[3][128][32];   // 48 KB
    __shared__ ushort Bs[3][4096];      // 24 KB
    const int t = threadIdx.x;
    const int wid = t >> 6, l = t & 63;
    const int lr = l & 15, lg = l >> 4;
    const int wrow0 = blockIdx.x * 128 + wid * 16;

    if (blockIdx.x == 0 && wid == 0) {   // finalize sum_attr (fixed order, deterministic)
        float v = bsum[l] + bsum[l + 64] + bsum[l + 128] + bsum[l + 192];
        v = wave_reduce_sum(v);
        if (l == 0) sc[0] = v;
    }

    const int srow = l >> 3;
    const int schunk = (l & 7) ^ srow;
    int g0 = wrow0 + srow;      if (g0 > NN - 1) g0 = NN - 1;
    int g1 = wrow0 + 8 + srow;  if (g1 > NN - 1) g1 = NN - 1;
    const float* sp0 = x + (size_t)g0 * FI + schunk * 4;
    const float* sp1 = x + (size_t)g1 * FI + schunk * 4;

    const ushort* bq0 = Wp + wid * 512 + l * 8;

    const int rs0 = (lg * 2)     ^ (lr & 7);
    const int rs1 = (lg * 2 + 1) ^ (lr & 7);

    f32x4 acc[8];
    #pragma unroll
    for (int c = 0; c < 8; ++c) acc[c] = (f32x4){0.f, 0.f, 0.f, 0.f};

#define STAGE(B, IT) do { \
    __builtin_amdgcn_global_load_lds( \
        (const __attribute__((address_space(1))) unsigned int*)(sp0 + (size_t)(IT) * 32), \
        (__attribute__((address_space(3))) unsigned int*)&As[B][wid * 16][0], 16, 0, 0); \
    __builtin_amdgcn_global_load_lds( \
        (const __attribute__((address_space(1))) unsigned int*)(sp1 + (size_t)(IT) * 32), \
        (__attribute__((address_space(3))) unsigned int*)&As[B][wid * 16 + 8][0], 16, 0, 0); \
    __builtin_amdgcn_global_load_lds( \
        (const __attribute__((address_space(1))) unsigned int*)(bq0 + (size_t)(IT) * 4096), \
        (__attribute__((address_space(3))) unsigned int*)&Bs[B][wid * 512], 16, 0, 0); \
} while (0)

    STAGE(0, 0);
    STAGE(1, 1);
    STAGE(2, 2);
    asm volatile("s_waitcnt vmcnt(6)" ::: "memory");    // stage 0's 3 insts landed
    __builtin_amdgcn_s_barrier();

    int bsel = 0;
    for (int it = 0; it < 40; ++it) {
        bfrag bfr[8];
        #pragma unroll
        for (int cg = 0; cg < 8; ++cg)
            bfr[cg] = *(const bfrag*)&Bs[bsel][cg * 512 + l * 8];

        float4 a0 = *(const float4*)&As[bsel][wid * 16 + lr][rs0 * 4];
        float4 a1 = *(const float4*)&As[bsel][wid * 16 + lr][rs1 * 4];
        bfrag af = cvt_frag(a0, a1);
        #pragma unroll
        for (int cg = 0; cg < 8; ++cg)
            acc[cg] = __builtin_amdgcn_mfma_f32_16x16x32_bf16(af, bfr[cg], acc[cg], 0, 0, 0);

        __builtin_amdgcn_s_barrier();                   // all waves done READING buf[bsel]
        if (it + 3 < 40) {
            STAGE(bsel, it + 3);
            asm volatile("s_waitcnt vmcnt(6)" ::: "memory");  // stage(it+1) landed
        } else if (it == 37) {
            asm volatile("s_waitcnt vmcnt(3)" ::: "memory");  // stage(38) landed
        } else if (it == 38) {
            asm volatile("s_waitcnt vmcnt(0)" ::: "memory");  // stage(39) landed
        }
        __builtin_amdgcn_s_barrier();                   // staged writes visible to all waves
        bsel = (bsel == 2) ? 0 : bsel + 1;
    }
#undef STAGE

    {   // K tail: step 40 (k0=1280, valid k<1284 in lg==0 low half); Wp zero-padded
        int rowc = wrow0 + lr; if (rowc > NN - 1) rowc = NN - 1;
        float4 a0t = make_float4(0.f, 0.f, 0.f, 0.f);
        if (lg == 0) a0t = *(const float4*)(x + (size_t)rowc * FI + 1280);
        bfrag af;
        af[0] = (short)f2bf(a0t.x); af[1] = (short)f2bf(a0t.y);
        af[2] = (short)f2bf(a0t.z); af[3] = (short)f2bf(a0t.w);
        af[4] = 0; af[5] = 0; af[6] = 0; af[7] = 0;
        const ushort* wqs = Wp + (size_t)40 * 4096 + l * 8;
        #pragma unroll
        for (int cg = 0; cg < 8; ++cg) {
            bfrag bf = *(const bfrag*)(wqs + cg * 512);
            acc[cg] = __builtin_amdgcn_mfma_f32_16x16x32_bf16(af, bf, acc[cg], 0, 0, 0);
        }
    }

    // h1 store (bf16)
    #pragma unroll
    for (int cg = 0; cg < 8; ++cg) {
        #pragma unroll
        for (int r = 0; r < 4; ++r) {
            int gr = wrow0 + lg * 4 + r;
            if (gr < NN) h1[(size_t)gr * HD + cg * 16 + lr] = f2bf(acc[cg][r]);
        }
    }

    // fused rowdot epilogue: as1/ad1[row] from fp32 acc (shfl_xor over 16-lane lr group)
    float av[8], dv[8];
    #pragma unroll
    for (int cg = 0; cg < 8; ++cg) {
        av[cg] = asrc[cg * 16 + lr];
        dv[cg] = adst[cg * 16 + lr];
    }
    #pragma unroll
    for (int r = 0; r < 4; ++r) {
        float s = 0.f, d = 0.f;
        #pragma unroll
        for (int cg = 0; cg < 8; ++cg) {
            s += acc[cg][r] * av[cg];
            d += acc[cg][r] * dv[cg];
        }
        #pragma unroll
        for (int off = 1; off < 16; off <<= 1) {
            s += __shfl_xor(s, off);
            d += __shfl_xor(d, off);
        }
        int gr = wrow0 + lg * 4 + r;
        if (lr == 0 && gr < NN) { as1[gr] = s; ad1[gr] = d; }
    }
}

// ---------------- place: fixed-bucket CSR (d*PAD), packed 8B record {src, al_h<<16 | attr_h} ----------------

__global__ void k_place(const int* __restrict__ ei, const float* __restrict__ eattr,
                        const float* __restrict__ sc,
                        const float* __restrict__ as1, const float* __restrict__ ad1,
                        int* cursor, int2* __restrict__ csr) {
    int e = blockIdx.x * blockDim.x + threadIdx.x;
    if (e >= NEP) return;
    int s, d; float av;
    if (e < NE) { s = ei[e]; d = ei[NE + e]; av = eattr[e]; }
    else        { s = d = e - NE; av = sc[0] * (1.0f / NE); }
    float a = as1[s] + ad1[d] + sc[1] * av;
    a = (a > 0.f) ? a : 0.2f * a;
    int pos = atomicAdd(&cursor[d], 1);
    if (pos - d * PAD < PAD)   // never taken for this input; memory-safety guard
        csr[pos] = make_int2(s, ((int)f2h(a) << 16) | (int)f2h(av));
}

// ---------------- layer 1 (fused): single-pass ONLINE softmax + PV + ELU + W2-dot ----------------

__global__ __launch_bounds__(256) void k_layer1(const int2* __restrict__ csr,
                                                const int* __restrict__ cursor,
                                                const ushort* __restrict__ h1,
                                                const float* __restrict__ b1,
                                                const float* __restrict__ W2,
                                                float* __restrict__ h2) {
    int wid = threadIdx.x >> 6, l = threadIdx.x & 63;
    int d = blockIdx.x * 4 + wid;
    if (d >= NN) return;
    int s0 = d * PAD;
    int n = cursor[d] - s0; if (n > PAD) n = PAD;

    float m = -INFINITY, den = 0.f, ax = 0.f, ay = 0.f;
    int i = 0;
    for (; i + 4 <= n; i += 4) {
        int2 e0 = csr[s0 + i],     e1 = csr[s0 + i + 1];
        int2 e2 = csr[s0 + i + 2], e3 = csr[s0 + i + 3];
        float a0 = h2f((ushort)(e0.y >> 16));
        float a1 = h2f((ushort)(e1.y >> 16));
        float a2 = h2f((ushort)(e2.y >> 16));
        float a3 = h2f((ushort)(e3.y >> 16));
        ushort2 hv0 = *(const ushort2*)&h1[(size_t)e0.x * HD + 2 * l];
        ushort2 hv1 = *(const ushort2*)&h1[(size_t)e1.x * HD + 2 * l];
        ushort2 hv2 = *(const ushort2*)&h1[(size_t)e2.x * HD + 2 * l];
        ushort2 hv3 = *(const ushort2*)&h1[(size_t)e3.x * HD + 2 * l];
        float mt = fmaxf(fmaxf(a0, a1), fmaxf(a2, a3));
        if (mt > m) {                      // wave-uniform branch
            float r = expf(m - mt);        // first tile: exp(-inf) = 0
            den *= r; ax *= r; ay *= r; m = mt;
        }
        float w0 = expf(a0 - m), w1 = expf(a1 - m);
        float w2 = expf(a2 - m), w3 = expf(a3 - m);
        den += w0 + w1 + w2 + w3;
        ax += w0 * bf2f(hv0.x) + w1 * bf2f(hv1.x) + w2 * bf2f(hv2.x) + w3 * bf2f(hv3.x);
        ay += w0 * bf2f(hv0.y) + w1 * bf2f(hv1.y) + w2 * bf2f(hv2.y) + w3 * bf2f(hv3.y);
    }
    for (; i < n; ++i) {
        int2 e0 = csr[s0 + i];
        float a0 = h2f((ushort)(e0.y >> 16));
        ushort2 hv0 = *(const ushort2*)&h1[(size_t)e0.x * HD + 2 * l];
        if (a0 > m) {
            float r = expf(m - a0);
            den *= r; ax *= r; ay *= r; m = a0;
        }
        float w0 = expf(a0 - m);
        den += w0;
        ax += w0 * bf2f(hv0.x);
        ay += w0 * bf2f(hv0.y);
    }
    float inv = 1.f / (den + 1e-16f);
    ax *= inv; ay *= inv;
    float2 bb = *(const float2*)&b1[2 * l];
    float2 w  = *(const float2*)&W2[2 * l];
    float a = ax + bb.x; a = (a > 0.f) ? a : (expf(a) - 1.f);
    float b = ay + bb.y; b = (b > 0.f) ? b : (expf(b) - 1.f);
    float p = a * w.x + b * w.y;
    p = wave_reduce_sum(p);
    if (l == 0) h2[d] = p;
}

// ---------------- layer 2 (fused, scalar): single-pass online softmax ----------------

__global__ __launch_bounds__(256) void k_layer2(const int2* __restrict__ csr,
                                                const int* __restrict__ cursor,
                                                const float* __restrict__ h2,
                                                const float* __restrict__ as2,
                                                const float* __restrict__ ad2,
                                                const float* __restrict__ sc,
                                                const float* __restrict__ b2,
                                                float* __restrict__ out) {
    int d = blockIdx.x * blockDim.x + threadIdx.x;
    if (d >= NN) return;
    int s0 = d * PAD;
    int n = cursor[d] - s0; if (n > PAD) n = PAD;
    float A = as2[0], D = ad2[0], c2 = sc[2];
    float hd = D * h2[d];

    float m = -INFINITY, den = 0.f, num = 0.f;
    int i = 0;
    for (; i + 4 <= n; i += 4) {
        int2 s_0 = csr[s0 + i],     s_1 = csr[s0 + i + 1];
        int2 s_2 = csr[s0 + i + 2], s_3 = csr[s0 + i + 3];
        float h0 = h2[s_0.x], h1v = h2[s_1.x], h2v = h2[s_2.x], h3 = h2[s_3.x];
        float a0 = A * h0 + hd + c2 * h2f((ushort)(s_0.y & 0xFFFF));
        float a1 = A * h1v + hd + c2 * h2f((ushort)(s_1.y & 0xFFFF));
        float a2 = A * h2v + hd + c2 * h2f((ushort)(s_2.y & 0xFFFF));
        float a3 = A * h3 + hd + c2 * h2f((ushort)(s_3.y & 0xFFFF));
        a0 = (a0 > 0.f) ? a0 : 0.2f * a0;
        a1 = (a1 > 0.f) ? a1 : 0.2f * a1;
        a2 = (a2 > 0.f) ? a2 : 0.2f * a2;
        a3 = (a3 > 0.f) ? a3 : 0.2f * a3;
        float mt = fmaxf(fmaxf(a0, a1), fmaxf(a2, a3));
        if (mt > m) {
            float r = expf(m - mt);
            den *= r; num *= r; m = mt;
        }
        float w0 = expf(a0 - m), w1 = expf(a1 - m);
        float w2 = expf(a2 - m), w3 = expf(a3 - m);
        den += w0 + w1 + w2 + w3;
        num += w0 * h0 + w1 * h1v + w2 * h2v + w3 * h3;
    }
    for (; i < n; ++i) {
        int2 sa = csr[s0 + i];
        float hs = h2[sa.x];
        float a = A * hs + hd + c2 * h2f((ushort)(sa.y & 0xFFFF));
        a = (a > 0.f) ? a : 0.2f * a;
        if (a > m) {
            float r = expf(m - a);
            den *= r; num *= r; m = a;
        }
        float wgt = expf(a - m);
        den += wgt;
        num += wgt * hs;
    }
    float v = num / (den + 1e-16f) + b2[0];
    out[d] = (v >= 0.f) ? v : 0.01f * v;
}

// ---------------- launch ----------------

extern "C" void kernel_launch(void* const* d_in, const int* in_sizes, int n_in,
                              void* d_out, int out_size, void* d_ws, size_t ws_size,
                              hipStream_t stream) {
    const float* x     = (const float*)d_in[0];
    const int*   ei    = (const int*)d_in[1];
    const float* eattr = (const float*)d_in[2];
    const float* W1    = (const float*)d_in[3];
    const float* asrc1 = (const float*)d_in[4];
    const float* adst1 = (const float*)d_in[5];
    const float* We1   = (const float*)d_in[6];
    const float* ae1   = (const float*)d_in[7];
    const float* b1    = (const float*)d_in[8];
    const float* W2    = (const float*)d_in[9];
    const float* as2   = (const float*)d_in[10];
    const float* ad2   = (const float*)d_in[11];
    const float* We2   = (const float*)d_in[12];
    const float* ae2   = (const float*)d_in[13];
    const float* b2    = (const float*)d_in[14];
    float* out = (float*)d_out;

    // workspace layout (~40 MB)
    ushort* h1  = (ushort*)d_ws;              // NH ushorts (12.8 MB)
    float* as1  = (float*)(h1 + (size_t)NH);  // NN
    float* ad1  = as1 + NN;
    float* h2   = ad1 + NN;
    float* sc   = h2 + NN;                    // 8 scalars
    float* bsum = sc + 8;                     // 256 partials
    int*   cursor = (int*)(bsum + 256);       // NN
    int2*  csr    = (int2*)(cursor + NN);     // NN*PAD int2 (25.6 MB)
    ushort* Wp  = (ushort*)(csr + (size_t)NN * PAD);  // WP_ELEMS bf16 (packed)

    k_pre<<<NBLK + 1 + WT_BLKS + 256, 256, 0, stream>>>(cursor, sc, We1, ae1, We2, ae2,
                                                        W1, Wp, eattr, bsum);

    k_gemm1_mfma<<<NROWB, 512, 0, stream>>>(x, Wp, h1, asrc1, adst1, as1, ad1, bsum, sc);

    k_place<<<(NEP + 255) / 256, 256, 0, stream>>>(ei, eattr, sc, as1, ad1, cursor, csr);

    k_layer1<<<(NN + 3) / 4, 256, 0, stream>>>(csr, cursor, h1, b1, W2, h2);
    k_layer2<<<(NN + 255) / 256, 256, 0, stream>>>(csr, cursor, h2, as2, ad2, sc, b2, out);
}